// Round 5
// baseline (1201.318 us; speedup 1.0000x reference)
//
#include <hip/hip_runtime.h>

typedef __bf16 bf16x8 __attribute__((ext_vector_type(8)));
typedef __bf16 bf16x4 __attribute__((ext_vector_type(4)));
typedef float f32x4 __attribute__((ext_vector_type(4)));
typedef float f32x16 __attribute__((ext_vector_type(16)));

#define MFMA16(a, b, c) __builtin_amdgcn_mfma_f32_16x16x32_bf16((a), (b), (c), 0, 0, 0)
#define MFMA32(a, b, c) __builtin_amdgcn_mfma_f32_32x32x16_bf16((a), (b), (c), 0, 0, 0)

static constexpr int SEQ = 4096;
static constexpr int DIM = 512;

typedef __attribute__((address_space(3))) void lds_void;
typedef __attribute__((address_space(1))) const void gbl_void;

__device__ __forceinline__ void glds16(const void* g, void* l) {
    __builtin_amdgcn_global_load_lds((gbl_void*)g, (lds_void*)l, 16, 0, 0);
}

__device__ __forceinline__ bf16x8 cvt8f(const float* __restrict__ p) {
    float4 f0 = *(const float4*)p;
    float4 f1 = *(const float4*)(p + 4);
    bf16x8 v;
    v[0] = (__bf16)f0.x; v[1] = (__bf16)f0.y; v[2] = (__bf16)f0.z; v[3] = (__bf16)f0.w;
    v[4] = (__bf16)f1.x; v[5] = (__bf16)f1.y; v[6] = (__bf16)f1.z; v[7] = (__bf16)f1.w;
    return v;
}

// ---------------------------------------------------------------------------
// fp32 -> bf16 converters
// ---------------------------------------------------------------------------
__global__ __launch_bounds__(256)
void cvt_f32_bf16(const float* __restrict__ in, __bf16* __restrict__ out) {
    const size_t i = ((size_t)blockIdx.x * 256 + threadIdx.x) * 8;
    *(bf16x8*)(out + i) = cvt8f(in + i);
}

__global__ __launch_bounds__(256)
void convert_w(const float* __restrict__ wq, const float* __restrict__ wk,
               const float* __restrict__ wv, const float* __restrict__ wo,
               __bf16* __restrict__ out)
{
    const int z = blockIdx.y;
    const float* src = (z == 0) ? wq : (z == 1) ? wk : (z == 2) ? wv : wo;
    __bf16* dst = out + (size_t)z * DIM * DIM;
    const int i = (blockIdx.x * 256 + threadIdx.x) * 8;
    *(bf16x8*)(dst + i) = cvt8f(src + i);
}

// ---------------------------------------------------------------------------
// Pure-bf16 m97-style GEMM: C = A @ B^T, 128x128 tile, BK=64, glds16 staging.
// TRANS: write output transposed (Vt[d][s]) via LDS-transpose epilogue.
// ---------------------------------------------------------------------------
template <bool TRANS>
__global__ __launch_bounds__(256, 3)
void gemm_bf16(const __bf16* __restrict__ Ap, const __bf16* __restrict__ Bp,
               __bf16* __restrict__ Cp)
{
    __shared__ __align__(16) char smem[128 * 132 * 2];   // 33792 B
    __bf16* As = (__bf16*)smem;                // [128][64]
    __bf16* Bs = (__bf16*)(smem + 16384);      // [128][64]

    const int tid  = threadIdx.x;
    const int wave = tid >> 6;
    const int lane = tid & 63;
    const int quad = lane >> 4;
    const int l16  = lane & 15;
    const int m0 = blockIdx.x * 128;
    const int n0 = blockIdx.y * 128;
    const int wm = (wave >> 1) * 64;
    const int wn = (wave & 1) * 64;

    f32x4 acc[4][4] = {};

    for (int k0 = 0; k0 < DIM; k0 += 64) {
        #pragma unroll
        for (int i = 0; i < 4; i++) {
            const int j = wave * 4 + i;
            const int c = j * 64 + lane;
            const int row = c >> 3, c8 = c & 7;
            glds16(Ap + (size_t)(m0 + row) * DIM + k0 + c8 * 8, &As[j * 512]);
            glds16(Bp + (size_t)(n0 + row) * DIM + k0 + c8 * 8, &Bs[j * 512]);
        }
        __syncthreads();
        #pragma unroll
        for (int kk = 0; kk < 2; kk++) {
            bf16x8 af[4], bg[4];
            #pragma unroll
            for (int mt = 0; mt < 4; mt++)
                af[mt] = *(const bf16x8*)&As[(wm + mt * 16 + l16) * 64 + kk * 32 + quad * 8];
            #pragma unroll
            for (int nt = 0; nt < 4; nt++)
                bg[nt] = *(const bf16x8*)&Bs[(wn + nt * 16 + l16) * 64 + kk * 32 + quad * 8];
            #pragma unroll
            for (int mt = 0; mt < 4; mt++)
                #pragma unroll
                for (int nt = 0; nt < 4; nt++)
                    acc[mt][nt] = MFMA16(af[mt], bg[nt], acc[mt][nt]);
        }
        __syncthreads();
    }

    if (!TRANS) {
        #pragma unroll
        for (int mt = 0; mt < 4; mt++)
            #pragma unroll
            for (int nt = 0; nt < 4; nt++)
                #pragma unroll
                for (int r = 0; r < 4; r++)
                    Cp[(size_t)(m0 + wm + mt * 16 + quad * 4 + r) * DIM
                       + n0 + wn + nt * 16 + l16] = (__bf16)acc[mt][nt][r];
    } else {
        __bf16* Tt = (__bf16*)smem;            // [128][132]
        #pragma unroll
        for (int mt = 0; mt < 4; mt++)
            #pragma unroll
            for (int nt = 0; nt < 4; nt++)
                #pragma unroll
                for (int r = 0; r < 4; r++)
                    Tt[(wm + mt * 16 + quad * 4 + r) * 132 + wn + nt * 16 + l16]
                        = (__bf16)acc[mt][nt][r];
        __syncthreads();
        const int nb  = m0 >> 12;
        const int s0m = m0 & 4095;
        const int d   = tid >> 1;
        const int sh  = (tid & 1) * 64;
        __bf16* dst = Cp + (size_t)nb * DIM * SEQ + (size_t)(n0 + d) * SEQ + s0m + sh;
        #pragma unroll
        for (int i = 0; i < 8; i++) {
            bf16x8 vv;
            #pragma unroll
            for (int e = 0; e < 8; e++) vv[e] = Tt[(sh + i * 8 + e) * 132 + d];
            *(bf16x8*)(dst + i * 8) = vv;
        }
    }
}

// ---------------------------------------------------------------------------
// Output GEMM: C(fp32) = A(bf16) @ Wo(bf16)^T + bias (m97 structure)
// ---------------------------------------------------------------------------
__global__ __launch_bounds__(256, 3)
void gemm_out(const __bf16* __restrict__ Ap, const __bf16* __restrict__ Bp,
              float* __restrict__ Cp, const float* __restrict__ bias)
{
    __shared__ __align__(16) __bf16 As[128 * 64];
    __shared__ __align__(16) __bf16 Bs[128 * 64];
    const int tid  = threadIdx.x;
    const int wave = tid >> 6;
    const int lane = tid & 63;
    const int quad = lane >> 4;
    const int l16  = lane & 15;
    const int m0 = blockIdx.x * 128;
    const int n0 = blockIdx.y * 128;
    const int wm = (wave >> 1) * 64;
    const int wn = (wave & 1) * 64;

    f32x4 acc[4][4] = {};

    for (int k0 = 0; k0 < DIM; k0 += 64) {
        #pragma unroll
        for (int i = 0; i < 4; i++) {
            const int j = wave * 4 + i;
            const int c = j * 64 + lane;
            const int row = c >> 3, c8 = c & 7;
            glds16(Ap + (size_t)(m0 + row) * DIM + k0 + c8 * 8, &As[j * 512]);
            glds16(Bp + (size_t)(n0 + row) * DIM + k0 + c8 * 8, &Bs[j * 512]);
        }
        __syncthreads();
        #pragma unroll
        for (int kk = 0; kk < 2; kk++) {
            bf16x8 af[4], bg[4];
            #pragma unroll
            for (int mt = 0; mt < 4; mt++)
                af[mt] = *(const bf16x8*)&As[(wm + mt * 16 + l16) * 64 + kk * 32 + quad * 8];
            #pragma unroll
            for (int nt = 0; nt < 4; nt++)
                bg[nt] = *(const bf16x8*)&Bs[(wn + nt * 16 + l16) * 64 + kk * 32 + quad * 8];
            #pragma unroll
            for (int mt = 0; mt < 4; mt++)
                #pragma unroll
                for (int nt = 0; nt < 4; nt++)
                    acc[mt][nt] = MFMA16(af[mt], bg[nt], acc[mt][nt]);
        }
        __syncthreads();
    }
    #pragma unroll
    for (int mt = 0; mt < 4; mt++)
        #pragma unroll
        for (int nt = 0; nt < 4; nt++)
            #pragma unroll
            for (int r = 0; r < 4; r++) {
                const int col = n0 + wn + nt * 16 + l16;
                Cp[(size_t)(m0 + wm + mt * 16 + quad * 4 + r) * DIM + col]
                    = acc[mt][nt][r] + bias[col];
            }
}

// ---------------------------------------------------------------------------
// Flash attention v5 — transposed scores (S^T = K @ Q^T), per-lane softmax.
// 512 thr / 8 waves, BM=32 q (lane axis!), BN=512 kcols/iter, 8 iters.
// Wave w: S^T kcol rows [64w,+64); PV O^T d-slice [64w,+64). Zero K/V dup.
// LDS 70 KB -> 2 blocks/CU co-resident. 2 barriers/iter.
// Softmax state m,l,alpha = per-lane scalars (q = lane&31) — no serial combine.
// P written as bf16x4 vectors (no scalar LDS scatter).
// ---------------------------------------------------------------------------
__global__ __launch_bounds__(512, 4)
void flash_attn(__bf16* __restrict__ Qp, const __bf16* __restrict__ Kp,
                const __bf16* __restrict__ Vt, const int* __restrict__ mask)
{
    constexpr float SCALE = 0.044194173824159216f;   // 1/sqrt(512)
    constexpr int PS = 520;                          // P row stride (elts)

    __shared__ __bf16 Qs[32 * 512];      // 32 KB, XOR-swizzled 16B chunks
    __shared__ __bf16 P[32 * PS];        // 33.3 KB, [q][kcol]
    __shared__ unsigned Wb[16 * 33];     // mask bits [word][q], 2.1 KB
    __shared__ float pmax[8][32];
    __shared__ float psum[8][32];

    const int bid  = blockIdx.x;
    const int n    = bid & 3;
    const int q0   = (bid >> 2) * 32;
    const int tid  = threadIdx.x;
    const int w    = tid >> 6;
    const int lane = tid & 63;
    const int l32  = lane & 31;
    const int half = lane >> 5;

    const __bf16* Qb = Qp + (size_t)n * SEQ * DIM;
    const __bf16* Kb = Kp + (size_t)n * SEQ * DIM;
    const __bf16* Vb = Vt + (size_t)n * DIM * SEQ;
    const int*    Mb = mask + (size_t)n * SEQ * SEQ;
    __bf16*       AO = Qp + (size_t)n * SEQ * DIM;   // alias; rows consumed first

    // ---- stage Q once (wave-uniform row per (i,w); full-row burst, no conflicts)
    #pragma unroll
    for (int i = 0; i < 4; i++) {
        const int row = i * 8 + w;
        const int c   = lane;
        const int pc  = (c & 56) | ((c & 7) ^ (row & 7));
        *(bf16x8*)&Qs[row * 512 + pc * 8] =
            *(const bf16x8*)(Qb + (size_t)(q0 + row) * DIM + c * 8);
    }
    __syncthreads();

    float m_reg = -__builtin_inff();
    float l_reg = 0.f;
    f32x16 o0 = {}, o1 = {};

    const int mq = tid >> 4, wd = tid & 15;

    for (int j = 0; j < 8; j++) {
        const int k0 = j * 512;

        // ---- mask loads (issued now, consumed after scores -> latency hidden)
        int4 mk[8];
        {
            const int* mp = Mb + (size_t)(q0 + mq) * SEQ + k0 + wd * 32;
            #pragma unroll
            for (int c = 0; c < 8; c++) mk[c] = *(const int4*)(mp + c * 4);
        }

        // ---- phase 1: S^T tile; wave w -> kcol rows [64w, 64w+64), q cols 0..31
        f32x16 s0 = {}, s1 = {};
        {
            const __bf16* kb = Kb + (size_t)(k0 + w * 64 + l32) * DIM + half * 8;
            #pragma unroll
            for (int ks = 0; ks < 32; ks++) {
                bf16x8 a0 = *(const bf16x8*)(kb + ks * 16);
                bf16x8 a1 = *(const bf16x8*)(kb + 32 * DIM + ks * 16);
                const int c  = ks * 2 + half;
                const int pc = (c & 56) | ((c & 7) ^ (l32 & 7));
                bf16x8 b = *(const bf16x8*)&Qs[l32 * 512 + pc * 8];
                s0 = MFMA32(a0, b, s0);
                s1 = MFMA32(a1, b, s1);
            }
        }

        // ---- pack mask word -> Wb[wd][q] (conflict-free stride 33)
        {
            unsigned wv = 0;
            #pragma unroll
            for (int c = 0; c < 8; c++) {
                wv |= (unsigned)(mk[c].x & 1) << (c * 4);
                wv |= (unsigned)(mk[c].y & 1) << (c * 4 + 1);
                wv |= (unsigned)(mk[c].z & 1) << (c * 4 + 2);
                wv |= (unsigned)(mk[c].w & 1) << (c * 4 + 3);
            }
            Wb[wd * 33 + mq] = wv;
        }

        // ---- per-lane partial max over this wave's 64 kcols (q = l32)
        {
            float mx = s0[0];
            #pragma unroll
            for (int r = 1; r < 16; r++) mx = fmaxf(mx, s0[r]);
            #pragma unroll
            for (int r = 0; r < 16; r++) mx = fmaxf(mx, s1[r]);
            mx = fmaxf(mx, __shfl_xor(mx, 32));
            if (half == 0) pmax[w][l32] = mx;
        }
        __syncthreads();   // A

        // ---- combine max (all lanes redundantly; per-lane scalar state)
        float mp_ = pmax[0][l32];
        #pragma unroll
        for (int w2 = 1; w2 < 8; w2++) mp_ = fmaxf(mp_, pmax[w2][l32]);
        const float mn = fmaxf(m_reg, mp_ * SCALE);
        const float alpha = __expf(m_reg - mn);
        m_reg = mn;

        // ---- rescale O
        #pragma unroll
        for (int r = 0; r < 16; r++) { o0[r] *= alpha; o1[r] *= alpha; }

        // ---- exp + mask + vectorized P write + partial lsum
        float lsum = 0.f;
        {
            const unsigned w0 = Wb[(2 * w) * 33 + l32] >> (half * 4);
            const unsigned w1 = Wb[(2 * w + 1) * 33 + l32] >> (half * 4);
            #pragma unroll
            for (int q2 = 0; q2 < 4; q2++) {
                bf16x4 pv0, pv1;
                #pragma unroll
                for (int rr = 0; rr < 4; rr++) {
                    const int r = q2 * 4 + rr;
                    const int bit = rr + 8 * q2;
                    float p0 = __expf(s0[r] * SCALE - mn);
                    float p1 = __expf(s1[r] * SCALE - mn);
                    p0 = ((w0 >> bit) & 1u) ? p0 : 0.f;
                    p1 = ((w1 >> bit) & 1u) ? p1 : 0.f;
                    lsum += p0 + p1;
                    pv0[rr] = (__bf16)p0;
                    pv1[rr] = (__bf16)p1;
                }
                const int cb = w * 64 + q2 * 8 + half * 4;
                *(bf16x4*)&P[l32 * PS + cb]      = pv0;
                *(bf16x4*)&P[l32 * PS + cb + 32] = pv1;
            }
            lsum += __shfl_xor(lsum, 32);
            if (half == 0) psum[w][l32] = lsum;
        }
        __syncthreads();   // B

        // ---- l update (per-lane)
        {
            float ls = psum[0][l32];
            #pragma unroll
            for (int w2 = 1; w2 < 8; w2++) ls += psum[w2][l32];
            l_reg = l_reg * alpha + ls;
        }

        // ---- PV: O^T = V^T @ P^T; wave d-slice [64w, 64w+64)
        {
            const __bf16* vb = Vb + (size_t)(w * 64 + l32) * SEQ + k0 + half * 8;
            #pragma unroll
            for (int ks = 0; ks < 32; ks++) {
                bf16x8 a0 = *(const bf16x8*)(vb + ks * 16);
                bf16x8 a1 = *(const bf16x8*)(vb + 32 * SEQ + ks * 16);
                bf16x8 b  = *(const bf16x8*)&P[l32 * PS + ks * 16 + half * 8];
                o0 = MFMA32(a0, b, o0);
                o1 = MFMA32(a1, b, o1);
            }
        }
    }

    // ---- epilogue: AO[q][d] = O^T[d][q] / l ; lane q = q0+l32, d in reg quads
    const float li = 1.f / l_reg;
    __bf16* ao = AO + (size_t)(q0 + l32) * DIM;
    #pragma unroll
    for (int q2 = 0; q2 < 4; q2++) {
        bf16x4 v0, v1;
        #pragma unroll
        for (int rr = 0; rr < 4; rr++) {
            v0[rr] = (__bf16)(o0[q2 * 4 + rr] * li);
            v1[rr] = (__bf16)(o1[q2 * 4 + rr] * li);
        }
        const int db = w * 64 + q2 * 8 + half * 4;
        *(bf16x4*)&ao[db]      = v0;
        *(bf16x4*)&ao[db + 32] = v1;
    }
}

// ---------------------------------------------------------------------------
extern "C" void kernel_launch(void* const* d_in, const int* in_sizes, int n_in,
                              void* d_out, int out_size, void* d_ws, size_t ws_size,
                              hipStream_t stream)
{
    const float* values = (const float*)d_in[0];
    const float* keys   = (const float*)d_in[1];
    const float* query  = (const float*)d_in[2];
    const int*   mask   = (const int*)d_in[3];
    const float* Wv = (const float*)d_in[4];
    const float* Wk = (const float*)d_in[5];
    const float* Wq = (const float*)d_in[6];
    const float* Wo = (const float*)d_in[7];
    const float* bo = (const float*)d_in[8];
    float* out = (float*)d_out;

    char* ws = (char*)d_ws;
    __bf16* Qp  = (__bf16*)(ws);                 // 16 MiB (AO aliases)
    __bf16* Kp  = (__bf16*)(ws + (16u << 20));   // 16 MiB
    __bf16* Vt  = (__bf16*)(ws + (32u << 20));   // 16 MiB
    __bf16* Abf = (__bf16*)(ws + (48u << 20));   // 16 MiB (reused 3x)
    __bf16* wbf = (__bf16*)(ws + (64u << 20));   // 2 MiB

    const int M = 4 * SEQ;  // 16384
    const dim3 gg(M / 128, DIM / 128);

    convert_w<<<dim3(128, 4), 256, 0, stream>>>(Wq, Wk, Wv, Wo, wbf);

    cvt_f32_bf16<<<4096, 256, 0, stream>>>(query, Abf);
    gemm_bf16<false><<<gg, 256, 0, stream>>>(Abf, wbf + 0 * DIM * DIM, Qp);

    cvt_f32_bf16<<<4096, 256, 0, stream>>>(keys, Abf);
    gemm_bf16<false><<<gg, 256, 0, stream>>>(Abf, wbf + 1 * DIM * DIM, Kp);

    cvt_f32_bf16<<<4096, 256, 0, stream>>>(values, Abf);
    gemm_bf16<true><<<gg, 256, 0, stream>>>(Abf, wbf + 2 * DIM * DIM, Vt);

    flash_attn<<<512, 512, 0, stream>>>(Qp, Kp, Vt, mask);

    gemm_out<<<gg, 256, 0, stream>>>(Qp /*AO*/, wbf + 3 * DIM * DIM, out, bo);
}

// Round 6
// 1009.169 us; speedup vs baseline: 1.1904x; 1.1904x over previous
//
#include <hip/hip_runtime.h>

typedef __bf16 bf16x8 __attribute__((ext_vector_type(8)));
typedef __bf16 bf16x4 __attribute__((ext_vector_type(4)));
typedef float f32x4 __attribute__((ext_vector_type(4)));
typedef float f32x16 __attribute__((ext_vector_type(16)));

#define MFMA16(a, b, c) __builtin_amdgcn_mfma_f32_16x16x32_bf16((a), (b), (c), 0, 0, 0)
#define MFMA32(a, b, c) __builtin_amdgcn_mfma_f32_32x32x16_bf16((a), (b), (c), 0, 0, 0)

static constexpr int SEQ = 4096;
static constexpr int DIM = 512;

typedef __attribute__((address_space(3))) void lds_void;
typedef __attribute__((address_space(1))) const void gbl_void;

__device__ __forceinline__ void glds16(const void* g, void* l) {
    __builtin_amdgcn_global_load_lds((gbl_void*)g, (lds_void*)l, 16, 0, 0);
}

__device__ __forceinline__ bf16x8 cvt8f(const float* __restrict__ p) {
    float4 f0 = *(const float4*)p;
    float4 f1 = *(const float4*)(p + 4);
    bf16x8 v;
    v[0] = (__bf16)f0.x; v[1] = (__bf16)f0.y; v[2] = (__bf16)f0.z; v[3] = (__bf16)f0.w;
    v[4] = (__bf16)f1.x; v[5] = (__bf16)f1.y; v[6] = (__bf16)f1.z; v[7] = (__bf16)f1.w;
    return v;
}

// ---------------------------------------------------------------------------
// fp32 -> bf16 converters
// ---------------------------------------------------------------------------
__global__ __launch_bounds__(256)
void cvt_f32_bf16(const float* __restrict__ in, __bf16* __restrict__ out) {
    const size_t i = ((size_t)blockIdx.x * 256 + threadIdx.x) * 8;
    *(bf16x8*)(out + i) = cvt8f(in + i);
}

__global__ __launch_bounds__(256)
void convert_w(const float* __restrict__ wq, const float* __restrict__ wk,
               const float* __restrict__ wv, const float* __restrict__ wo,
               __bf16* __restrict__ out)
{
    const int z = blockIdx.y;
    const float* src = (z == 0) ? wq : (z == 1) ? wk : (z == 2) ? wv : wo;
    __bf16* dst = out + (size_t)z * DIM * DIM;
    const int i = (blockIdx.x * 256 + threadIdx.x) * 8;
    *(bf16x8*)(dst + i) = cvt8f(src + i);
}

// ---------------------------------------------------------------------------
// Pure-bf16 m97-style GEMM: C = A @ B^T, 128x128 tile, BK=64, glds16 staging.
// TRANS: write output transposed (Vt[d][s]) via LDS-transpose epilogue.
// ---------------------------------------------------------------------------
template <bool TRANS>
__global__ __launch_bounds__(256, 3)
void gemm_bf16(const __bf16* __restrict__ Ap, const __bf16* __restrict__ Bp,
               __bf16* __restrict__ Cp)
{
    __shared__ __align__(16) char smem[128 * 132 * 2];   // 33792 B
    __bf16* As = (__bf16*)smem;                // [128][64]
    __bf16* Bs = (__bf16*)(smem + 16384);      // [128][64]

    const int tid  = threadIdx.x;
    const int wave = tid >> 6;
    const int lane = tid & 63;
    const int quad = lane >> 4;
    const int l16  = lane & 15;
    const int m0 = blockIdx.x * 128;
    const int n0 = blockIdx.y * 128;
    const int wm = (wave >> 1) * 64;
    const int wn = (wave & 1) * 64;

    f32x4 acc[4][4] = {};

    for (int k0 = 0; k0 < DIM; k0 += 64) {
        #pragma unroll
        for (int i = 0; i < 4; i++) {
            const int j = wave * 4 + i;
            const int c = j * 64 + lane;
            const int row = c >> 3, c8 = c & 7;
            glds16(Ap + (size_t)(m0 + row) * DIM + k0 + c8 * 8, &As[j * 512]);
            glds16(Bp + (size_t)(n0 + row) * DIM + k0 + c8 * 8, &Bs[j * 512]);
        }
        __syncthreads();
        #pragma unroll
        for (int kk = 0; kk < 2; kk++) {
            bf16x8 af[4], bg[4];
            #pragma unroll
            for (int mt = 0; mt < 4; mt++)
                af[mt] = *(const bf16x8*)&As[(wm + mt * 16 + l16) * 64 + kk * 32 + quad * 8];
            #pragma unroll
            for (int nt = 0; nt < 4; nt++)
                bg[nt] = *(const bf16x8*)&Bs[(wn + nt * 16 + l16) * 64 + kk * 32 + quad * 8];
            #pragma unroll
            for (int mt = 0; mt < 4; mt++)
                #pragma unroll
                for (int nt = 0; nt < 4; nt++)
                    acc[mt][nt] = MFMA16(af[mt], bg[nt], acc[mt][nt]);
        }
        __syncthreads();
    }

    if (!TRANS) {
        #pragma unroll
        for (int mt = 0; mt < 4; mt++)
            #pragma unroll
            for (int nt = 0; nt < 4; nt++)
                #pragma unroll
                for (int r = 0; r < 4; r++)
                    Cp[(size_t)(m0 + wm + mt * 16 + quad * 4 + r) * DIM
                       + n0 + wn + nt * 16 + l16] = (__bf16)acc[mt][nt][r];
    } else {
        __bf16* Tt = (__bf16*)smem;            // [128][132]
        #pragma unroll
        for (int mt = 0; mt < 4; mt++)
            #pragma unroll
            for (int nt = 0; nt < 4; nt++)
                #pragma unroll
                for (int r = 0; r < 4; r++)
                    Tt[(wm + mt * 16 + quad * 4 + r) * 132 + wn + nt * 16 + l16]
                        = (__bf16)acc[mt][nt][r];
        __syncthreads();
        const int nb  = m0 >> 12;
        const int s0m = m0 & 4095;
        const int d   = tid >> 1;
        const int sh  = (tid & 1) * 64;
        __bf16* dst = Cp + (size_t)nb * DIM * SEQ + (size_t)(n0 + d) * SEQ + s0m + sh;
        #pragma unroll
        for (int i = 0; i < 8; i++) {
            bf16x8 vv;
            #pragma unroll
            for (int e = 0; e < 8; e++) vv[e] = Tt[(sh + i * 8 + e) * 132 + d];
            *(bf16x8*)(dst + i * 8) = vv;
        }
    }
}

// ---------------------------------------------------------------------------
// Output GEMM: C(fp32) = A(bf16) @ Wo(bf16)^T + bias (m97 structure)
// ---------------------------------------------------------------------------
__global__ __launch_bounds__(256, 3)
void gemm_out(const __bf16* __restrict__ Ap, const __bf16* __restrict__ Bp,
              float* __restrict__ Cp, const float* __restrict__ bias)
{
    __shared__ __align__(16) __bf16 As[128 * 64];
    __shared__ __align__(16) __bf16 Bs[128 * 64];
    const int tid  = threadIdx.x;
    const int wave = tid >> 6;
    const int lane = tid & 63;
    const int quad = lane >> 4;
    const int l16  = lane & 15;
    const int m0 = blockIdx.x * 128;
    const int n0 = blockIdx.y * 128;
    const int wm = (wave >> 1) * 64;
    const int wn = (wave & 1) * 64;

    f32x4 acc[4][4] = {};

    for (int k0 = 0; k0 < DIM; k0 += 64) {
        #pragma unroll
        for (int i = 0; i < 4; i++) {
            const int j = wave * 4 + i;
            const int c = j * 64 + lane;
            const int row = c >> 3, c8 = c & 7;
            glds16(Ap + (size_t)(m0 + row) * DIM + k0 + c8 * 8, &As[j * 512]);
            glds16(Bp + (size_t)(n0 + row) * DIM + k0 + c8 * 8, &Bs[j * 512]);
        }
        __syncthreads();
        #pragma unroll
        for (int kk = 0; kk < 2; kk++) {
            bf16x8 af[4], bg[4];
            #pragma unroll
            for (int mt = 0; mt < 4; mt++)
                af[mt] = *(const bf16x8*)&As[(wm + mt * 16 + l16) * 64 + kk * 32 + quad * 8];
            #pragma unroll
            for (int nt = 0; nt < 4; nt++)
                bg[nt] = *(const bf16x8*)&Bs[(wn + nt * 16 + l16) * 64 + kk * 32 + quad * 8];
            #pragma unroll
            for (int mt = 0; mt < 4; mt++)
                #pragma unroll
                for (int nt = 0; nt < 4; nt++)
                    acc[mt][nt] = MFMA16(af[mt], bg[nt], acc[mt][nt]);
        }
        __syncthreads();
    }
    #pragma unroll
    for (int mt = 0; mt < 4; mt++)
        #pragma unroll
        for (int nt = 0; nt < 4; nt++)
            #pragma unroll
            for (int r = 0; r < 4; r++) {
                const int col = n0 + wn + nt * 16 + l16;
                Cp[(size_t)(m0 + wm + mt * 16 + quad * 4 + r) * DIM + col]
                    = acc[mt][nt][r] + bias[col];
            }
}

// ---------------------------------------------------------------------------
// Flash attention v5b — transposed scores (S^T = K @ Q^T), per-lane softmax.
// 512 thr / 8 waves, BM=32 q (lane axis), BN=512 kcols/iter, 8 iters.
// launch_bounds(512,2): 256-VGPR cap — R5's (512,4) forced 64 VGPRs and
// spilled o/s every iteration (WRITE_SIZE 638 MB). Mask packed to LDS
// BEFORE the score phase (no 32-reg int4 prefetch held across 64 MFMAs).
// ---------------------------------------------------------------------------
__global__ __launch_bounds__(512, 2)
void flash_attn(__bf16* __restrict__ Qp, const __bf16* __restrict__ Kp,
                const __bf16* __restrict__ Vt, const int* __restrict__ mask)
{
    constexpr float SCALE = 0.044194173824159216f;   // 1/sqrt(512)
    constexpr int PS = 520;                          // P row stride (elts)

    __shared__ __bf16 Qs[32 * 512];      // 32 KB, XOR-swizzled 16B chunks
    __shared__ __bf16 P[32 * PS];        // 33.3 KB, [q][kcol]
    __shared__ unsigned Wb[16 * 33];     // mask bits [word][q], 2.1 KB
    __shared__ float pmax[8][32];
    __shared__ float psum[8][32];

    const int bid  = blockIdx.x;
    const int n    = bid & 3;
    const int q0   = (bid >> 2) * 32;
    const int tid  = threadIdx.x;
    const int w    = tid >> 6;
    const int lane = tid & 63;
    const int l32  = lane & 31;
    const int half = lane >> 5;

    const __bf16* Qb = Qp + (size_t)n * SEQ * DIM;
    const __bf16* Kb = Kp + (size_t)n * SEQ * DIM;
    const __bf16* Vb = Vt + (size_t)n * DIM * SEQ;
    const int*    Mb = mask + (size_t)n * SEQ * SEQ;
    __bf16*       AO = Qp + (size_t)n * SEQ * DIM;   // alias; rows consumed first

    // ---- stage Q once (wave-uniform row per (i,w); full-row burst)
    #pragma unroll
    for (int i = 0; i < 4; i++) {
        const int row = i * 8 + w;
        const int c   = lane;
        const int pc  = (c & 56) | ((c & 7) ^ (row & 7));
        *(bf16x8*)&Qs[row * 512 + pc * 8] =
            *(const bf16x8*)(Qb + (size_t)(q0 + row) * DIM + c * 8);
    }
    __syncthreads();

    float m_reg = -__builtin_inff();
    float l_reg = 0.f;
    f32x16 o0 = {}, o1 = {};

    const int mq = tid >> 4, wd = tid & 15;

    for (int j = 0; j < 8; j++) {
        const int k0 = j * 512;

        // ---- mask load + pack -> LDS (before scores: 32-reg footprint is
        //      transient; TLP across 16 waves/CU hides the HBM latency)
        {
            const int* mp = Mb + (size_t)(q0 + mq) * SEQ + k0 + wd * 32;
            unsigned wv = 0;
            #pragma unroll
            for (int c = 0; c < 8; c++) {
                int4 m4 = *(const int4*)(mp + c * 4);
                wv |= (unsigned)(m4.x & 1) << (c * 4);
                wv |= (unsigned)(m4.y & 1) << (c * 4 + 1);
                wv |= (unsigned)(m4.z & 1) << (c * 4 + 2);
                wv |= (unsigned)(m4.w & 1) << (c * 4 + 3);
            }
            Wb[wd * 33 + mq] = wv;
        }

        // ---- phase 1: S^T tile; wave w -> kcol rows [64w, 64w+64), q cols 0..31
        f32x16 s0 = {}, s1 = {};
        {
            const __bf16* kb = Kb + (size_t)(k0 + w * 64 + l32) * DIM + half * 8;
            #pragma unroll
            for (int ks = 0; ks < 32; ks++) {
                bf16x8 a0 = *(const bf16x8*)(kb + ks * 16);
                bf16x8 a1 = *(const bf16x8*)(kb + 32 * DIM + ks * 16);
                const int c  = ks * 2 + half;
                const int pc = (c & 56) | ((c & 7) ^ (l32 & 7));
                bf16x8 b = *(const bf16x8*)&Qs[l32 * 512 + pc * 8];
                s0 = MFMA32(a0, b, s0);
                s1 = MFMA32(a1, b, s1);
            }
        }

        // ---- per-lane partial max over this wave's 64 kcols (q = l32)
        {
            float mx = s0[0];
            #pragma unroll
            for (int r = 1; r < 16; r++) mx = fmaxf(mx, s0[r]);
            #pragma unroll
            for (int r = 0; r < 16; r++) mx = fmaxf(mx, s1[r]);
            mx = fmaxf(mx, __shfl_xor(mx, 32));
            if (half == 0) pmax[w][l32] = mx;
        }
        __syncthreads();   // A

        // ---- combine max (all lanes redundantly; per-lane scalar state)
        float mp_ = pmax[0][l32];
        #pragma unroll
        for (int w2 = 1; w2 < 8; w2++) mp_ = fmaxf(mp_, pmax[w2][l32]);
        const float mn = fmaxf(m_reg, mp_ * SCALE);
        const float alpha = __expf(m_reg - mn);
        m_reg = mn;

        // ---- rescale O
        #pragma unroll
        for (int r = 0; r < 16; r++) { o0[r] *= alpha; o1[r] *= alpha; }

        // ---- exp + mask + vectorized P write + partial lsum
        float lsum = 0.f;
        {
            const unsigned w0 = Wb[(2 * w) * 33 + l32] >> (half * 4);
            const unsigned w1 = Wb[(2 * w + 1) * 33 + l32] >> (half * 4);
            #pragma unroll
            for (int q2 = 0; q2 < 4; q2++) {
                bf16x4 pv0, pv1;
                #pragma unroll
                for (int rr = 0; rr < 4; rr++) {
                    const int r = q2 * 4 + rr;
                    const int bit = rr + 8 * q2;
                    float p0 = __expf(s0[r] * SCALE - mn);
                    float p1 = __expf(s1[r] * SCALE - mn);
                    p0 = ((w0 >> bit) & 1u) ? p0 : 0.f;
                    p1 = ((w1 >> bit) & 1u) ? p1 : 0.f;
                    lsum += p0 + p1;
                    pv0[rr] = (__bf16)p0;
                    pv1[rr] = (__bf16)p1;
                }
                const int cb = w * 64 + q2 * 8 + half * 4;
                *(bf16x4*)&P[l32 * PS + cb]      = pv0;
                *(bf16x4*)&P[l32 * PS + cb + 32] = pv1;
            }
            lsum += __shfl_xor(lsum, 32);
            if (half == 0) psum[w][l32] = lsum;
        }
        __syncthreads();   // B

        // ---- l update (per-lane)
        {
            float ls = psum[0][l32];
            #pragma unroll
            for (int w2 = 1; w2 < 8; w2++) ls += psum[w2][l32];
            l_reg = l_reg * alpha + ls;
        }

        // ---- PV: O^T = V^T @ P^T; wave d-slice [64w, 64w+64)
        {
            const __bf16* vb = Vb + (size_t)(w * 64 + l32) * SEQ + k0 + half * 8;
            #pragma unroll
            for (int ks = 0; ks < 32; ks++) {
                bf16x8 a0 = *(const bf16x8*)(vb + ks * 16);
                bf16x8 a1 = *(const bf16x8*)(vb + 32 * SEQ + ks * 16);
                bf16x8 b  = *(const bf16x8*)&P[l32 * PS + ks * 16 + half * 8];
                o0 = MFMA32(a0, b, o0);
                o1 = MFMA32(a1, b, o1);
            }
        }
    }

    // ---- epilogue: AO[q][d] = O^T[d][q] / l ; lane q = q0+l32
    const float li = 1.f / l_reg;
    __bf16* ao = AO + (size_t)(q0 + l32) * DIM;
    #pragma unroll
    for (int q2 = 0; q2 < 4; q2++) {
        bf16x4 v0, v1;
        #pragma unroll
        for (int rr = 0; rr < 4; rr++) {
            v0[rr] = (__bf16)(o0[q2 * 4 + rr] * li);
            v1[rr] = (__bf16)(o1[q2 * 4 + rr] * li);
        }
        const int db = w * 64 + q2 * 8 + half * 4;
        *(bf16x4*)&ao[db]      = v0;
        *(bf16x4*)&ao[db + 32] = v1;
    }
}

// ---------------------------------------------------------------------------
extern "C" void kernel_launch(void* const* d_in, const int* in_sizes, int n_in,
                              void* d_out, int out_size, void* d_ws, size_t ws_size,
                              hipStream_t stream)
{
    const float* values = (const float*)d_in[0];
    const float* keys   = (const float*)d_in[1];
    const float* query  = (const float*)d_in[2];
    const int*   mask   = (const int*)d_in[3];
    const float* Wv = (const float*)d_in[4];
    const float* Wk = (const float*)d_in[5];
    const float* Wq = (const float*)d_in[6];
    const float* Wo = (const float*)d_in[7];
    const float* bo = (const float*)d_in[8];
    float* out = (float*)d_out;

    char* ws = (char*)d_ws;
    __bf16* Qp  = (__bf16*)(ws);                 // 16 MiB (AO aliases)
    __bf16* Kp  = (__bf16*)(ws + (16u << 20));   // 16 MiB
    __bf16* Vt  = (__bf16*)(ws + (32u << 20));   // 16 MiB
    __bf16* Abf = (__bf16*)(ws + (48u << 20));   // 16 MiB (reused 3x)
    __bf16* wbf = (__bf16*)(ws + (64u << 20));   // 2 MiB

    const int M = 4 * SEQ;  // 16384
    const dim3 gg(M / 128, DIM / 128);

    convert_w<<<dim3(128, 4), 256, 0, stream>>>(Wq, Wk, Wv, Wo, wbf);

    cvt_f32_bf16<<<4096, 256, 0, stream>>>(query, Abf);
    gemm_bf16<false><<<gg, 256, 0, stream>>>(Abf, wbf + 0 * DIM * DIM, Qp);

    cvt_f32_bf16<<<4096, 256, 0, stream>>>(keys, Abf);
    gemm_bf16<false><<<gg, 256, 0, stream>>>(Abf, wbf + 1 * DIM * DIM, Kp);

    cvt_f32_bf16<<<4096, 256, 0, stream>>>(values, Abf);
    gemm_bf16<true><<<gg, 256, 0, stream>>>(Abf, wbf + 2 * DIM * DIM, Vt);

    flash_attn<<<512, 512, 0, stream>>>(Qp, Kp, Vt, mask);

    gemm_out<<<gg, 256, 0, stream>>>(Qp /*AO*/, wbf + 3 * DIM * DIM, out, bo);
}

// Round 7
// 808.283 us; speedup vs baseline: 1.4863x; 1.2485x over previous
//
#include <hip/hip_runtime.h>

typedef __bf16 bf16x8 __attribute__((ext_vector_type(8)));
typedef __bf16 bf16x4 __attribute__((ext_vector_type(4)));
typedef float f32x4 __attribute__((ext_vector_type(4)));
typedef float f32x16 __attribute__((ext_vector_type(16)));

#define MFMA16(a, b, c) __builtin_amdgcn_mfma_f32_16x16x32_bf16((a), (b), (c), 0, 0, 0)
#define MFMA32(a, b, c) __builtin_amdgcn_mfma_f32_32x32x16_bf16((a), (b), (c), 0, 0, 0)

static constexpr int SEQ = 4096;
static constexpr int DIM = 512;

typedef __attribute__((address_space(3))) void lds_void;
typedef __attribute__((address_space(1))) const void gbl_void;

__device__ __forceinline__ void glds16(const void* g, void* l) {
    __builtin_amdgcn_global_load_lds((gbl_void*)g, (lds_void*)l, 16, 0, 0);
}

__device__ __forceinline__ bf16x8 cvt8f(const float* __restrict__ p) {
    float4 f0 = *(const float4*)p;
    float4 f1 = *(const float4*)(p + 4);
    bf16x8 v;
    v[0] = (__bf16)f0.x; v[1] = (__bf16)f0.y; v[2] = (__bf16)f0.z; v[3] = (__bf16)f0.w;
    v[4] = (__bf16)f1.x; v[5] = (__bf16)f1.y; v[6] = (__bf16)f1.z; v[7] = (__bf16)f1.w;
    return v;
}

// ---------------------------------------------------------------------------
// fp32 -> bf16 converters
// ---------------------------------------------------------------------------
__global__ __launch_bounds__(256)
void cvt_f32_bf16(const float* __restrict__ in, __bf16* __restrict__ out) {
    const size_t i = ((size_t)blockIdx.x * 256 + threadIdx.x) * 8;
    *(bf16x8*)(out + i) = cvt8f(in + i);
}

__global__ __launch_bounds__(256)
void convert_w(const float* __restrict__ wq, const float* __restrict__ wk,
               const float* __restrict__ wv, const float* __restrict__ wo,
               __bf16* __restrict__ out)
{
    const int z = blockIdx.y;
    const float* src = (z == 0) ? wq : (z == 1) ? wk : (z == 2) ? wv : wo;
    __bf16* dst = out + (size_t)z * DIM * DIM;
    const int i = (blockIdx.x * 256 + threadIdx.x) * 8;
    *(bf16x8*)(dst + i) = cvt8f(src + i);
}

// ---------------------------------------------------------------------------
// Pure-bf16 m97-style GEMM: C = A @ B^T, 128x128 tile, BK=64, glds16 staging.
// TRANS: write output transposed (Vt[d][s]) via LDS-transpose epilogue.
// ---------------------------------------------------------------------------
template <bool TRANS>
__global__ __launch_bounds__(256, 3)
void gemm_bf16(const __bf16* __restrict__ Ap, const __bf16* __restrict__ Bp,
               __bf16* __restrict__ Cp)
{
    __shared__ __align__(16) char smem[128 * 132 * 2];   // 33792 B
    __bf16* As = (__bf16*)smem;                // [128][64]
    __bf16* Bs = (__bf16*)(smem + 16384);      // [128][64]

    const int tid  = threadIdx.x;
    const int wave = tid >> 6;
    const int lane = tid & 63;
    const int quad = lane >> 4;
    const int l16  = lane & 15;
    const int m0 = blockIdx.x * 128;
    const int n0 = blockIdx.y * 128;
    const int wm = (wave >> 1) * 64;
    const int wn = (wave & 1) * 64;

    f32x4 acc[4][4] = {};

    for (int k0 = 0; k0 < DIM; k0 += 64) {
        #pragma unroll
        for (int i = 0; i < 4; i++) {
            const int j = wave * 4 + i;
            const int c = j * 64 + lane;
            const int row = c >> 3, c8 = c & 7;
            glds16(Ap + (size_t)(m0 + row) * DIM + k0 + c8 * 8, &As[j * 512]);
            glds16(Bp + (size_t)(n0 + row) * DIM + k0 + c8 * 8, &Bs[j * 512]);
        }
        __syncthreads();
        #pragma unroll
        for (int kk = 0; kk < 2; kk++) {
            bf16x8 af[4], bg[4];
            #pragma unroll
            for (int mt = 0; mt < 4; mt++)
                af[mt] = *(const bf16x8*)&As[(wm + mt * 16 + l16) * 64 + kk * 32 + quad * 8];
            #pragma unroll
            for (int nt = 0; nt < 4; nt++)
                bg[nt] = *(const bf16x8*)&Bs[(wn + nt * 16 + l16) * 64 + kk * 32 + quad * 8];
            #pragma unroll
            for (int mt = 0; mt < 4; mt++)
                #pragma unroll
                for (int nt = 0; nt < 4; nt++)
                    acc[mt][nt] = MFMA16(af[mt], bg[nt], acc[mt][nt]);
        }
        __syncthreads();
    }

    if (!TRANS) {
        #pragma unroll
        for (int mt = 0; mt < 4; mt++)
            #pragma unroll
            for (int nt = 0; nt < 4; nt++)
                #pragma unroll
                for (int r = 0; r < 4; r++)
                    Cp[(size_t)(m0 + wm + mt * 16 + quad * 4 + r) * DIM
                       + n0 + wn + nt * 16 + l16] = (__bf16)acc[mt][nt][r];
    } else {
        __bf16* Tt = (__bf16*)smem;            // [128][132]
        #pragma unroll
        for (int mt = 0; mt < 4; mt++)
            #pragma unroll
            for (int nt = 0; nt < 4; nt++)
                #pragma unroll
                for (int r = 0; r < 4; r++)
                    Tt[(wm + mt * 16 + quad * 4 + r) * 132 + wn + nt * 16 + l16]
                        = (__bf16)acc[mt][nt][r];
        __syncthreads();
        const int nb  = m0 >> 12;
        const int s0m = m0 & 4095;
        const int d   = tid >> 1;
        const int sh  = (tid & 1) * 64;
        __bf16* dst = Cp + (size_t)nb * DIM * SEQ + (size_t)(n0 + d) * SEQ + s0m + sh;
        #pragma unroll
        for (int i = 0; i < 8; i++) {
            bf16x8 vv;
            #pragma unroll
            for (int e = 0; e < 8; e++) vv[e] = Tt[(sh + i * 8 + e) * 132 + d];
            *(bf16x8*)(dst + i * 8) = vv;
        }
    }
}

// ---------------------------------------------------------------------------
// Output GEMM: C(fp32) = A(bf16) @ Wo(bf16)^T + bias (m97 structure)
// ---------------------------------------------------------------------------
__global__ __launch_bounds__(256, 3)
void gemm_out(const __bf16* __restrict__ Ap, const __bf16* __restrict__ Bp,
              float* __restrict__ Cp, const float* __restrict__ bias)
{
    __shared__ __align__(16) __bf16 As[128 * 64];
    __shared__ __align__(16) __bf16 Bs[128 * 64];
    const int tid  = threadIdx.x;
    const int wave = tid >> 6;
    const int lane = tid & 63;
    const int quad = lane >> 4;
    const int l16  = lane & 15;
    const int m0 = blockIdx.x * 128;
    const int n0 = blockIdx.y * 128;
    const int wm = (wave >> 1) * 64;
    const int wn = (wave & 1) * 64;

    f32x4 acc[4][4] = {};

    for (int k0 = 0; k0 < DIM; k0 += 64) {
        #pragma unroll
        for (int i = 0; i < 4; i++) {
            const int j = wave * 4 + i;
            const int c = j * 64 + lane;
            const int row = c >> 3, c8 = c & 7;
            glds16(Ap + (size_t)(m0 + row) * DIM + k0 + c8 * 8, &As[j * 512]);
            glds16(Bp + (size_t)(n0 + row) * DIM + k0 + c8 * 8, &Bs[j * 512]);
        }
        __syncthreads();
        #pragma unroll
        for (int kk = 0; kk < 2; kk++) {
            bf16x8 af[4], bg[4];
            #pragma unroll
            for (int mt = 0; mt < 4; mt++)
                af[mt] = *(const bf16x8*)&As[(wm + mt * 16 + l16) * 64 + kk * 32 + quad * 8];
            #pragma unroll
            for (int nt = 0; nt < 4; nt++)
                bg[nt] = *(const bf16x8*)&Bs[(wn + nt * 16 + l16) * 64 + kk * 32 + quad * 8];
            #pragma unroll
            for (int mt = 0; mt < 4; mt++)
                #pragma unroll
                for (int nt = 0; nt < 4; nt++)
                    acc[mt][nt] = MFMA16(af[mt], bg[nt], acc[mt][nt]);
        }
        __syncthreads();
    }
    #pragma unroll
    for (int mt = 0; mt < 4; mt++)
        #pragma unroll
        for (int nt = 0; nt < 4; nt++)
            #pragma unroll
            for (int r = 0; r < 4; r++) {
                const int col = n0 + wn + nt * 16 + l16;
                Cp[(size_t)(m0 + wm + mt * 16 + quad * 4 + r) * DIM + col]
                    = acc[mt][nt][r] + bias[col];
            }
}

// ---------------------------------------------------------------------------
// Flash attention v7 — m97-style LDS staging for K/V via swizzle-compensated
// global_load_lds. 512 thr / 8 waves, BM=64 q, KC=256 kcols/iter, 16 iters.
// S^T = K@Q^T (q on lane axis, 2 q-halves/lane), per-lane softmax state.
// K staged [256 kc][64 d] x8 chunks; V staged [256 d][64 kc] x8 chunks into
// one shared 32KB buffer. 256 blocks = exactly 1/CU (single round).
// LDS 137 KB. launch_bounds(512,2): 256-VGPR cap, no spill.
// ---------------------------------------------------------------------------
__global__ __launch_bounds__(512, 2)
void flash_attn(__bf16* __restrict__ Qp, const __bf16* __restrict__ Kp,
                const __bf16* __restrict__ Vt, const int* __restrict__ mask)
{
    constexpr float SCALE = 0.044194173824159216f;   // 1/sqrt(512)

    __shared__ __bf16 Qs[64 * 512];     // 64 KB, XOR-swizzled 16B chunks
    __shared__ __bf16 KV[256 * 64];     // 32 KB staging (K or V chunk)
    __shared__ __bf16 P[64 * 256];      // 32 KB, swizzled
    __shared__ unsigned Wb[8 * 66];     // mask bits [word][q]
    __shared__ float pmax[8 * 66];
    __shared__ float psum[8 * 66];

    const int bid  = blockIdx.x;
    const int n    = bid & 3;            // batch -> XCD-local K/V
    const int q0   = (bid >> 2) * 64;
    const int tid  = threadIdx.x;
    const int w    = tid >> 6;
    const int lane = tid & 63;
    const int l32  = lane & 31;
    const int half = lane >> 5;
    const int r8   = lane >> 3;          // 0..7
    const int c8   = lane & 7;
    const int gc   = c8 ^ r8;            // swizzle-compensated global chunk

    const __bf16* Qb = Qp + (size_t)n * SEQ * DIM;
    const __bf16* Kb = Kp + (size_t)n * SEQ * DIM;
    const __bf16* Vb = Vt + (size_t)n * DIM * SEQ;
    const int*    Mb = mask + (size_t)n * SEQ * SEQ;
    __bf16*       AO = Qp + (size_t)n * SEQ * DIM;   // alias; rows consumed first

    // ---- stage Q once via DMA (source chunk permuted to realize XOR swizzle)
    #pragma unroll
    for (int i = 0; i < 8; i++) {
        const int row = i * 8 + w;
        const int cs  = (lane & 56) | ((lane & 7) ^ (row & 7));
        glds16(Qb + (size_t)(q0 + row) * DIM + cs * 8, &Qs[row * 512]);
    }

    float m0 = -__builtin_inff(), m1 = -__builtin_inff();
    float l0 = 0.f, l1 = 0.f;
    f32x16 o00 = {}, o01 = {}, o10 = {}, o11 = {};   // [h][qh]

    const int mq = tid >> 3;   // 0..63 (mask q-row)
    const int wd = tid & 7;    // 0..7  (mask word)

    #pragma unroll 1
    for (int j = 0; j < 16; j++) {
        const int k0 = j * 256;

        // ---- mask prefetch into regs (drains at first stage barrier)
        int4 mk[8];
        {
            const int* mp = Mb + (size_t)(q0 + mq) * SEQ + k0 + wd * 32;
            #pragma unroll
            for (int c = 0; c < 8; c++) mk[c] = *(const int4*)(mp + c * 4);
        }

        // ---- phase 1: S^T scores, 8 staged K chunks of [256 kc][64 d]
        f32x16 s0 = {}, s1 = {};
        #pragma unroll 1
        for (int dc = 0; dc < 8; dc++) {
            #pragma unroll
            for (int i = 0; i < 4; i++) {
                const int R = (i * 8 + w) * 8 + r8;
                glds16(Kb + (size_t)(k0 + R) * DIM + dc * 64 + gc * 8,
                       &KV[(i * 8 + w) * 512]);
            }
            __syncthreads();
            #pragma unroll
            for (int ks = 0; ks < 4; ks++) {
                const int row = 32 * w + l32;                 // kcol (A rows)
                const int ca  = (2 * ks + half) ^ (row & 7);
                bf16x8 a = *(const bf16x8*)&KV[row * 64 + ca * 8];
                const int cq = dc * 8 + 2 * ks + half;        // Q d-chunk
                const int pq = (cq & 56) | ((cq & 7) ^ (l32 & 7));
                bf16x8 b0 = *(const bf16x8*)&Qs[l32 * 512 + pq * 8];
                bf16x8 b1 = *(const bf16x8*)&Qs[(32 + l32) * 512 + pq * 8];
                s0 = MFMA32(a, b0, s0);
                s1 = MFMA32(a, b1, s1);
            }
            __syncthreads();
        }

        // ---- pack mask words -> Wb[wd][q]
        {
            unsigned wv = 0;
            #pragma unroll
            for (int c = 0; c < 8; c++) {
                wv |= (unsigned)(mk[c].x & 1) << (c * 4);
                wv |= (unsigned)(mk[c].y & 1) << (c * 4 + 1);
                wv |= (unsigned)(mk[c].z & 1) << (c * 4 + 2);
                wv |= (unsigned)(mk[c].w & 1) << (c * 4 + 3);
            }
            Wb[wd * 66 + mq] = wv;
        }
        // ---- per-lane partial max over this wave's 32 kcols (raw scores)
        {
            float mx0 = s0[0], mx1 = s1[0];
            #pragma unroll
            for (int r = 1; r < 16; r++) { mx0 = fmaxf(mx0, s0[r]); mx1 = fmaxf(mx1, s1[r]); }
            mx0 = fmaxf(mx0, __shfl_xor(mx0, 32));
            mx1 = fmaxf(mx1, __shfl_xor(mx1, 32));
            if (half == 0) pmax[w * 66 + l32]      = mx0;
            else           pmax[w * 66 + 32 + l32] = mx1;
        }
        __syncthreads();   // A (Wb + pmax visible)

        // ---- combine max; per-lane softmax state for q=l32 (0) / q=32+l32 (1)
        float mp0 = pmax[l32], mp1 = pmax[32 + l32];
        #pragma unroll
        for (int w2 = 1; w2 < 8; w2++) {
            mp0 = fmaxf(mp0, pmax[w2 * 66 + l32]);
            mp1 = fmaxf(mp1, pmax[w2 * 66 + 32 + l32]);
        }
        const float mn0 = fmaxf(m0, mp0 * SCALE);
        const float mn1 = fmaxf(m1, mp1 * SCALE);
        const float a0 = __expf(m0 - mn0);
        const float a1 = __expf(m1 - mn1);
        m0 = mn0; m1 = mn1;
        #pragma unroll
        for (int r = 0; r < 16; r++) {
            o00[r] *= a0; o10[r] *= a0;
            o01[r] *= a1; o11[r] *= a1;
        }

        // ---- exp + mask + vectorized P write + partial lsum
        float ls0 = 0.f, ls1 = 0.f;
        {
            const unsigned wm0 = Wb[w * 66 + l32];
            const unsigned wm1 = Wb[w * 66 + 32 + l32];
            #pragma unroll
            for (int g = 0; g < 4; g++) {
                bf16x4 pv0, pv1;
                #pragma unroll
                for (int r4 = 0; r4 < 4; r4++) {
                    const int r = g * 4 + r4;
                    const int bit = g * 8 + half * 4 + r4;
                    float p0 = __expf(s0[r] * SCALE - mn0);
                    float p1 = __expf(s1[r] * SCALE - mn1);
                    p0 = ((wm0 >> bit) & 1u) ? p0 : 0.f;
                    p1 = ((wm1 >> bit) & 1u) ? p1 : 0.f;
                    ls0 += p0; ls1 += p1;
                    pv0[r4] = (__bf16)p0;
                    pv1[r4] = (__bf16)p1;
                }
                const int c  = 4 * w + g;                       // kcol chunk 0..31
                const int cp = (c & 24) | ((c & 7) ^ (l32 & 7)); // q&7 same both halves
                *(bf16x4*)&P[l32 * 256 + cp * 8 + 4 * half]        = pv0;
                *(bf16x4*)&P[(32 + l32) * 256 + cp * 8 + 4 * half] = pv1;
            }
            ls0 += __shfl_xor(ls0, 32);
            ls1 += __shfl_xor(ls1, 32);
            if (half == 0) psum[w * 66 + l32]      = ls0;
            else           psum[w * 66 + 32 + l32] = ls1;
        }
        __syncthreads();   // B (P + psum ready)

        {
            float ss0 = 0.f, ss1 = 0.f;
            #pragma unroll
            for (int w2 = 0; w2 < 8; w2++) {
                ss0 += psum[w2 * 66 + l32];
                ss1 += psum[w2 * 66 + 32 + l32];
            }
            l0 = l0 * a0 + ss0;
            l1 = l1 * a1 + ss1;
        }

        // ---- phase 3: PV, 8 staged V chunks of [256 d][64 kc]
        #pragma unroll 1
        for (int h = 0; h < 2; h++) {
            #pragma unroll 1
            for (int kc2 = 0; kc2 < 4; kc2++) {
                #pragma unroll
                for (int i = 0; i < 4; i++) {
                    const int R = (i * 8 + w) * 8 + r8;        // local d-row
                    glds16(Vb + (size_t)(h * 256 + R) * SEQ + k0 + kc2 * 64 + gc * 8,
                           &KV[(i * 8 + w) * 512]);
                }
                __syncthreads();
                #pragma unroll
                for (int ks = 0; ks < 4; ks++) {
                    const int row = 32 * w + l32;              // local d (A rows)
                    const int ca  = (2 * ks + half) ^ (row & 7);
                    bf16x8 a = *(const bf16x8*)&KV[row * 64 + ca * 8];
                    const int ck = kc2 * 8 + 2 * ks + half;    // P kcol chunk
                    const int cp = (ck & 24) | ((ck & 7) ^ (l32 & 7));
                    bf16x8 b0 = *(const bf16x8*)&P[l32 * 256 + cp * 8];
                    bf16x8 b1 = *(const bf16x8*)&P[(32 + l32) * 256 + cp * 8];
                    if (h == 0) { o00 = MFMA32(a, b0, o00); o01 = MFMA32(a, b1, o01); }
                    else        { o10 = MFMA32(a, b0, o10); o11 = MFMA32(a, b1, o11); }
                }
                __syncthreads();
            }
        }
    }

    // ---- epilogue: AO[q][d] = O^T[d][q] / l
    const float li0 = 1.f / l0, li1 = 1.f / l1;
    __bf16* ao0 = AO + (size_t)(q0 + l32) * DIM;
    __bf16* ao1 = AO + (size_t)(q0 + 32 + l32) * DIM;
    #pragma unroll
    for (int h = 0; h < 2; h++) {
        #pragma unroll
        for (int g = 0; g < 4; g++) {
            bf16x4 v00, v01;
            #pragma unroll
            for (int r4 = 0; r4 < 4; r4++) {
                const int r = g * 4 + r4;
                v00[r4] = (__bf16)((h ? o10[r] : o00[r]) * li0);
                v01[r4] = (__bf16)((h ? o11[r] : o01[r]) * li1);
            }
            const int d = h * 256 + 32 * w + g * 8 + 4 * half;
            *(bf16x4*)&ao0[d] = v00;
            *(bf16x4*)&ao1[d] = v01;
        }
    }
}

// ---------------------------------------------------------------------------
extern "C" void kernel_launch(void* const* d_in, const int* in_sizes, int n_in,
                              void* d_out, int out_size, void* d_ws, size_t ws_size,
                              hipStream_t stream)
{
    const float* values = (const float*)d_in[0];
    const float* keys   = (const float*)d_in[1];
    const float* query  = (const float*)d_in[2];
    const int*   mask   = (const int*)d_in[3];
    const float* Wv = (const float*)d_in[4];
    const float* Wk = (const float*)d_in[5];
    const float* Wq = (const float*)d_in[6];
    const float* Wo = (const float*)d_in[7];
    const float* bo = (const float*)d_in[8];
    float* out = (float*)d_out;

    char* ws = (char*)d_ws;
    __bf16* Qp  = (__bf16*)(ws);                 // 16 MiB (AO aliases)
    __bf16* Kp  = (__bf16*)(ws + (16u << 20));   // 16 MiB
    __bf16* Vt  = (__bf16*)(ws + (32u << 20));   // 16 MiB
    __bf16* Abf = (__bf16*)(ws + (48u << 20));   // 16 MiB (reused 3x)
    __bf16* wbf = (__bf16*)(ws + (64u << 20));   // 2 MiB

    const int M = 4 * SEQ;  // 16384
    const dim3 gg(M / 128, DIM / 128);

    convert_w<<<dim3(128, 4), 256, 0, stream>>>(Wq, Wk, Wv, Wo, wbf);

    cvt_f32_bf16<<<4096, 256, 0, stream>>>(query, Abf);
    gemm_bf16<false><<<gg, 256, 0, stream>>>(Abf, wbf + 0 * DIM * DIM, Qp);

    cvt_f32_bf16<<<4096, 256, 0, stream>>>(keys, Abf);
    gemm_bf16<false><<<gg, 256, 0, stream>>>(Abf, wbf + 1 * DIM * DIM, Kp);

    cvt_f32_bf16<<<4096, 256, 0, stream>>>(values, Abf);
    gemm_bf16<true><<<gg, 256, 0, stream>>>(Abf, wbf + 2 * DIM * DIM, Vt);

    flash_attn<<<256, 512, 0, stream>>>(Qp, Kp, Vt, mask);

    gemm_out<<<gg, 256, 0, stream>>>(Qp /*AO*/, wbf + 3 * DIM * DIM, out, bo);
}